// Round 1
// baseline (26877.979 us; speedup 1.0000x reference)
//
#include <hip/hip_runtime.h>
#include <hip/hip_bf16.h>
#include <hip/hip_fp16.h>

// Persistent dataflow RNN for MI355X (gfx950).
//   SEQ=4096, HID=2048, 4 layers.
//
// R7: XCD-local recurrence. R6's per-step cost (~2.37us) is dominated by the
// IC (Infinity Cache) round trip of the h-broadcast: agent-scope stores+loads
// bypass L2 because each layer's 64 WGs were spread over an XCD *pair*
// ({l, l+4} under blockIdx%8 round-robin). Now: grid=512, layer = blockIdx&7,
// residues 4..7 exit -> each layer's 64 WGs sit on ONE XCD (2 blocks/CU on
// its 32 CUs). Producers still publish with agent scope (sc1 write-through,
// required for the cross-XCD x pipeline), but the layer's own h-pollers use
// sc0-only loads (bypass L1, served by the SHARED per-XCD L2) -> the serial
// h round trip shrinks from IC (~800-1200cy) to L2 (~200-300cy) latency.
// The cross-XCD x-dependency is off the critical cycle: it only adds a
// constant per-layer pipeline offset.
// Safety: parity tags make any staleness = spinning, never wrong data. If
// the blockIdx->XCD mapping or sc0 semantics differ, lanes fall back to full
// agent (sc0 sc1) loads after FAST_TRIES polls -> correct under ANY mapping.
// Also new: per-lane partial retry (done lanes exec-mask off -> less hot-line
// contention), publish store moved ahead of the out[] store.
// Carried from R6: tag-in-data single-trip protocol, 512 thr / 8 waves,
// 128 VGPRs/lane pinned fp16 weight fragments, no fences in the loop.

#define SEQ 4096
#define HID 2048
#define NL 4
#define WGS_PER_LAYER 64
#define ROWS_PER_WG 32
#define KCAT 4096      // concat(x, h) elements
#define NT 32          // MFMA k-tiles per wave (k=1024 per wave, 4 k-ranges)
#define FAST_TRIES 8   // sc0-only poll attempts before agent fallback

typedef _Float16 f16x8 __attribute__((ext_vector_type(8)));
typedef float f32x4 __attribute__((ext_vector_type(4)));
typedef unsigned int u32x4 __attribute__((ext_vector_type(4)));
typedef unsigned long long u64;

__device__ __align__(16) _Float16 g_xin[(size_t)SEQ * HID];      // 16 MB
__device__ __align__(16) u64 g_ring[NL][SEQ][HID / 4];           // 67 MB (fp16 packed + tag LSBs)

// 8192 x 1024 = 8,388,608 = SEQ*HID = NL*SEQ*(HID/4) u64 — one grid does both.
__global__ void prep_kernel(const float* __restrict__ x) {
  size_t i = (size_t)blockIdx.x * blockDim.x + threadIdx.x;
  if (i < (size_t)SEQ * HID) g_xin[i] = (_Float16)x[i];
  if (i < (size_t)NL * SEQ * (HID / 4)) {
    size_t t = (i >> 9) & (SEQ - 1);                 // 512 u64 per (l,t) region
    unsigned int pat = (unsigned int)((t & 1) ^ 1);  // anti-parity tag
    u64 p64 = (u64)pat | ((u64)pat << 32);
    __hip_atomic_store(((u64*)g_ring) + i, p64, __ATOMIC_RELAXED,
                       __HIP_MEMORY_SCOPE_AGENT);    // visible at IC scope
  }
}

// 16B load, bypass L1 only -> coherence point = this XCD's L2 (fast path for
// same-XCD producer/consumer). Not expressible via HIP scopes; inline asm.
__device__ __forceinline__ u32x4 ld16_near(const void* p) {
  u32x4 r;
  asm volatile("global_load_dwordx4 %0, %1, off sc0\n\ts_waitcnt vmcnt(0)"
               : "=v"(r) : "v"(p) : "memory");
  return r;
}
// 16B load, bypass L1+L2 -> IC truth (agent scope). Fallback + cross-XCD x.
__device__ __forceinline__ u32x4 ld16_far(const void* p) {
  u32x4 r;
  asm volatile("global_load_dwordx4 %0, %1, off sc0 sc1\n\ts_waitcnt vmcnt(0)"
               : "=v"(r) : "v"(p) : "memory");
  return r;
}
__device__ __forceinline__ bool tags_ok(u32x4 v, unsigned int exp) {
  return ((v.x & 1u) == exp) & ((v.y & 1u) == exp) &
         ((v.z & 1u) == exp) & ((v.w & 1u) == exp);
}

__global__ __launch_bounds__(512, 4) void rnn_kernel(
    const float* __restrict__ wih, const float* __restrict__ whh,
    float* __restrict__ out) {
  const int xcd = blockIdx.x & 7;   // assumed round-robin XCD id (perf hint
  if (xcd >= NL) return;            //  only — tags+fallback keep correctness)
  const int layer = xcd;            // layer l lives entirely on XCD l
  const int wg    = blockIdx.x >> 3;  // 0..63 within layer
  const int tid   = threadIdx.x;
  const int lane  = tid & 63;
  const int wave  = tid >> 6;         // 8 waves
  const int rb    = wave >> 2;        // row block: 0 -> rows 0..15, 1 -> 16..31
  const int kq    = wave & 3;         // k-range 0..3 (1024 k each)
  const int m     = lane & 15;
  const int q     = lane >> 4;
  const int row   = wg * ROWS_PER_WG + rb * 16 + m;

  __shared__ __align__(16) _Float16 cat[KCAT];      // [0,2048)=x_t [2048,4096)=h_{t-1}
  __shared__ __align__(16) float partials[8][16];   // [wave][row-in-16]

  // ---- one-time: weights -> registers as fp16 A-fragments (128 VGPRs) ----
  // A layout (16x16x32): lane holds A[m][ktile + q*8 + j], j=0..7
  f32x4 afrag[NT];
  {
    const float* wl = wih + (size_t)layer * HID * HID + (size_t)row * HID;
    const float* wr = whh + (size_t)layer * HID * HID + (size_t)row * HID - HID;
#pragma unroll
    for (int i = 0; i < NT; ++i) {
      int kabs = kq * 1024 + i * 32 + q * 8;   // 1024-aligned ranges: never straddle 2048
      const float* src = (kabs < HID) ? (wl + kabs) : (wr + kabs);
      f32x4 w0 = *(const f32x4*)(src);
      f32x4 w1 = *(const f32x4*)(src + 4);
      f16x8 a;
      a[0] = (_Float16)w0[0]; a[1] = (_Float16)w0[1];
      a[2] = (_Float16)w0[2]; a[3] = (_Float16)w0[3];
      a[4] = (_Float16)w1[0]; a[5] = (_Float16)w1[1];
      a[6] = (_Float16)w1[2]; a[7] = (_Float16)w1[3];
      afrag[i] = __builtin_bit_cast(f32x4, a);
    }
#pragma unroll
    for (int i = 0; i < NT; ++i) asm volatile("" : "+v"(afrag[i]));  // pin
  }

  for (int t = 0; t < SEQ; ++t) {
    // ---- stage concat(x_t, h_{t-1}). Per-lane poll: each lane loops until
    //      ITS 16B is fresh (done lanes exec-masked off -> partial retry). ----
    {
      u32x4 v = {0u, 0u, 0u, 0u};
      if (tid < 256) {
        if (layer == 0) {
          v = *(const u32x4*)(g_xin + (size_t)t * HID + (size_t)tid * 8);
        } else {
          // x from the previous layer: other XCD -> agent (IC) loads.
          const u32x4* src = (const u32x4*)&g_ring[layer - 1][t][0] + tid;
          const unsigned int exp = (unsigned int)(t & 1);
          int it = 0;
          for (;;) {
            v = ld16_far(src);
            if (tags_ok(v, exp)) break;
            if (++it > (1 << 20)) break;  // never hang the harness
            __builtin_amdgcn_s_sleep(1);
          }
        }
      } else if (t > 0) {
        // h from OWN layer: same XCD -> sc0/L2 fast path, agent fallback.
        const u32x4* src = (const u32x4*)&g_ring[layer][t - 1][0] + (tid - 256);
        const unsigned int exp = (unsigned int)((t - 1) & 1);
        int it = 0;
        for (;;) {
          v = (it < FAST_TRIES) ? ld16_near(src) : ld16_far(src);
          if (tags_ok(v, exp)) break;
          if (++it > (1 << 20)) break;
          if (it >= FAST_TRIES) __builtin_amdgcn_s_sleep(1);
        }
      }
      ((u32x4*)cat)[tid] = v;
    }
    __syncthreads();

    // ---- MFMA: 16 rows x own 1024-k range. B = h broadcast to 16 cols ----
    f32x4 acc0 = {0.f, 0.f, 0.f, 0.f}, acc1 = {0.f, 0.f, 0.f, 0.f};
    const f16x8* bb = (const f16x8*)cat;
#pragma unroll
    for (int i = 0; i < NT; i += 2) {
      f16x8 b0 = bb[kq * 128 + i * 4 + q];
      f16x8 b1 = bb[kq * 128 + (i + 1) * 4 + q];
      acc0 = __builtin_amdgcn_mfma_f32_16x16x32_f16(
          __builtin_bit_cast(f16x8, afrag[i]), b0, acc0, 0, 0, 0);
      acc1 = __builtin_amdgcn_mfma_f32_16x16x32_f16(
          __builtin_bit_cast(f16x8, afrag[i + 1]), b1, acc1, 0, 0, 0);
    }
    f32x4 accs = acc0 + acc1;
    // D layout: col=lane&15 (all equal), row=(lane>>4)*4+reg
    if (m == 0) *(f32x4*)&partials[wave][q * 4] = accs;
    __syncthreads();

    // ---- wave 0: reduce 4 k-partials per row, relu, publish (store == flag).
    //      Publish FIRST (it's the serial path), out[] store after. ----
    if (tid < ROWS_PER_WG) {
      int rbb = tid >> 4, rr = tid & 15;
      float s = partials[rbb * 4 + 0][rr] + partials[rbb * 4 + 1][rr] +
                partials[rbb * 4 + 2][rr] + partials[rbb * 4 + 3][rr];
      s = fmaxf(s, 0.f);
      int gr = wg * ROWS_PER_WG + tid;
      unsigned int hb = (unsigned int)__builtin_bit_cast(unsigned short, (_Float16)s);
      unsigned int up = __shfl_down(hb, 1);          // odd row's bits
      if ((tid & 1) == 0) {
        unsigned int word = (hb & 0xFFFEu) | (unsigned int)(t & 1) | (up << 16);
        unsigned int* dst = (unsigned int*)&g_ring[layer][t][0] + (gr >> 1);
        __hip_atomic_store(dst, word, __ATOMIC_RELAXED, __HIP_MEMORY_SCOPE_AGENT);
      }
      if (layer == NL - 1) {
        out[(size_t)t * HID + gr] = s;                      // output[0, t, :]
        if (t == SEQ - 1) out[(size_t)SEQ * HID + gr] = s;  // h_last
      }
    }
    // no drain, no flag: the tagged store above is the publication.
  }
}

extern "C" void kernel_launch(void* const* d_in, const int* in_sizes, int n_in,
                              void* d_out, int out_size, void* d_ws, size_t ws_size,
                              hipStream_t stream) {
  const float* x   = (const float*)d_in[0];
  const float* wih = (const float*)d_in[1];
  const float* whh = (const float*)d_in[2];
  float* out = (float*)d_out;

  prep_kernel<<<8192, 1024, 0, stream>>>(x);
  // 512 blocks: residue r = blockIdx%8 -> XCD r (assumed round-robin).
  // Residues 0..3 carry layers 0..3 (64 WGs = 2 blocks/CU on one XCD);
  // residues 4..7 exit immediately. Correctness does not depend on the
  // mapping (tags + agent fallback) — only the fast path does.
  rnn_kernel<<<512, 512, 0, stream>>>(wih, whh, out);
}

// Round 2
// 10424.597 us; speedup vs baseline: 2.5783x; 2.5783x over previous
//
#include <hip/hip_runtime.h>
#include <hip/hip_bf16.h>
#include <hip/hip_fp16.h>

// Persistent dataflow RNN for MI355X (gfx950).
//   SEQ=4096, HID=2048, 4 layers. Grid 256 (R6 layout: layer = blockIdx&3).
//
// R8: hierarchical h-broadcast via XCD-elected relays.
// R7 post-mortem: __launch_bounds__(512,4) capped VGPRs at 64 -> the 128-VGPR
// afrag spilled to scratch (FETCH 385MB->7.5GB, 2.8x slower). Restored (512,2).
// R6 analysis: 5700cy/step >> latency sum (~2300cy). Gap = IC hot-line
// serialization: each layer's 4KB h (32 lines) polled by ~500-1000 waves/line
// per step (64 WGs x 4 h-waves + next layer's 256 x-waves + retries).
// Fix: one relay WG per (layer, XCD) — elected at runtime via the REAL
// XCC_ID hwreg + atomic ticket, so no dispatch-mapping assumption — is the
// ONLY IC poller (8 relay waves/line). It re-publishes polled words per-lane
// into g_mirror[src_layer][xcd][t] with sc0 stores that stay in the local L2;
// the other 31 WGs poll the mirror with sc0 loads (L2 latency, no IC
// contention). Tags ride verbatim; mirror is SEQ-indexed (no ABA); prep
// anti-parity-tags it; consumers fall back to agent(IC) ring loads after
// FAST_TRIES and permanently latch far if the fallback's FIRST try keeps
// succeeding (= mirror provably stale, not merely late). Worst case ==
// R6 behavior + bounded warm-up waste; never wrong, never hung.
// Carried: tag-in-data protocol, 512 thr / 8 waves, 128 VGPRs/lane pinned
// fp16 weights, relaxed agent publication, publish-before-out ordering.

#define SEQ 4096
#define HID 2048
#define NL 4
#define WGS_PER_LAYER 64
#define ROWS_PER_WG 32
#define KCAT 4096      // concat(x, h) elements
#define NT 32          // MFMA k-tiles per wave (k=1024 per wave, 4 k-ranges)
#define FAST_TRIES 24  // sc0/L2 mirror polls before agent fallback
#define LATCH_N 16     // provably-stale fallbacks before latching far

typedef _Float16 f16x8 __attribute__((ext_vector_type(8)));
typedef float f32x4 __attribute__((ext_vector_type(4)));
typedef unsigned int u32x4 __attribute__((ext_vector_type(4)));
typedef unsigned long long u64;

__device__ __align__(16) _Float16 g_xin[(size_t)SEQ * HID];      // 16 MB
__device__ __align__(16) u64 g_ring[NL][SEQ][HID / 4];           // 67 MB (fp16 packed + tag LSBs)
__device__ __align__(16) u64 g_mirror[NL][8][SEQ][HID / 4];      // 512 MB per-XCD L2 mirrors
__device__ int g_elect[NL][8];                                   // relay election tickets

// Grid 65536 x 1024 = 67,108,864 = NL*8*SEQ*(HID/4) — covers mirror exactly;
// ring (8.4M u64), xin (8.4M f16), elect (32 int) ride the low indices.
__global__ void prep_kernel(const float* __restrict__ x) {
  size_t i = (size_t)blockIdx.x * blockDim.x + threadIdx.x;
  size_t t = (i >> 9) & (SEQ - 1);                 // 512 u64 per t-region (ring AND mirror layout)
  unsigned int pat = (unsigned int)((t & 1) ^ 1);  // anti-parity tag
  u64 p64 = (u64)pat | ((u64)pat << 32);
  if (i < (size_t)SEQ * HID) g_xin[i] = (_Float16)x[i];
  if (i < (size_t)NL * SEQ * (HID / 4))
    __hip_atomic_store(((u64*)g_ring) + i, p64, __ATOMIC_RELAXED,
                       __HIP_MEMORY_SCOPE_AGENT);
  if (i < (size_t)NL * 8 * SEQ * (HID / 4))
    __hip_atomic_store(((u64*)g_mirror) + i, p64, __ATOMIC_RELAXED,
                       __HIP_MEMORY_SCOPE_AGENT);
  if (i < NL * 8) ((int*)g_elect)[i] = 0;          // re-arm election every launch
}

// 16B load, bypass L1 only -> served by this XCD's shared L2 (mirror fast path).
__device__ __forceinline__ u32x4 ld16_near(const void* p) {
  u32x4 r;
  asm volatile("global_load_dwordx4 %0, %1, off sc0\n\ts_waitcnt vmcnt(0)"
               : "=v"(r) : "v"(p) : "memory");
  return r;
}
// 16B load, bypass L1+L2 -> IC truth (agent scope). Relay + fallback path.
__device__ __forceinline__ u32x4 ld16_far(const void* p) {
  u32x4 r;
  asm volatile("global_load_dwordx4 %0, %1, off sc0 sc1\n\ts_waitcnt vmcnt(0)"
               : "=v"(r) : "v"(p) : "memory");
  return r;
}
// 16B store, bypass L1, land in local L2 (NOT sc1: must not be pushed to IC).
__device__ __forceinline__ void st16_l2(void* p, u32x4 v) {
  asm volatile("global_store_dwordx4 %0, %1, off sc0" :: "v"(p), "v"(v) : "memory");
}
__device__ __forceinline__ bool tags_ok(u32x4 v, unsigned int exp) {
  return ((v.x & 1u) == exp) & ((v.y & 1u) == exp) &
         ((v.z & 1u) == exp) & ((v.w & 1u) == exp);
}

// Relay: agent-poll the ring; per-lane, the instant a quad is fresh, copy it
// (tags included) into the local-L2 mirror. Returns the polled quad.
__device__ __forceinline__ u32x4 relay_poll(const u32x4* rsrc, u32x4* mdst,
                                            unsigned int exp) {
  u32x4 v = {0u, 0u, 0u, 0u};
  bool done = false;
  int it = 0;
  while (__ballot(!done)) {
    if (!done) {
      u32x4 nv = ld16_far(rsrc);
      if (tags_ok(nv, exp)) { st16_l2(mdst, nv); v = nv; done = true; }
    }
    if (++it > (1 << 20)) break;   // never hang the harness
    if (!done) __builtin_amdgcn_s_sleep(1);
  }
  return v;
}

// Consumer: poll local-L2 mirror (cheap); after FAST_TRIES fall back to the
// agent ring (always correct). If the fallback's FIRST try succeeds, the data
// had long been published and the mirror path is stale -> count; latch far.
__device__ __forceinline__ u32x4 cons_poll(const u32x4* msrc, const u32x4* rsrc,
                                           unsigned int exp, int& use_near,
                                           int& near_fail) {
  u32x4 v;
  if (use_near) {
    for (int it = 0; it < FAST_TRIES; ++it) {
      v = ld16_near(msrc);
      if (tags_ok(v, exp)) return v;
    }
  }
  int fit = 0;
  for (;;) {
    v = ld16_far(rsrc);
    if (tags_ok(v, exp)) break;
    if (++fit > (1 << 20)) break;
    __builtin_amdgcn_s_sleep(1);
  }
  if (use_near && fit == 0 && ++near_fail >= LATCH_N) use_near = 0;
  return v;
}

__global__ __launch_bounds__(512, 2) void rnn_kernel(
    const float* __restrict__ wih, const float* __restrict__ whh,
    float* __restrict__ out) {
  const int layer = blockIdx.x & 3;
  const int wg    = blockIdx.x >> 2;  // 0..63 within layer
  const int tid   = threadIdx.x;
  const int lane  = tid & 63;
  const int wave  = tid >> 6;         // 8 waves
  const int rb    = wave >> 2;        // row block: 0 -> rows 0..15, 1 -> 16..31
  const int kq    = wave & 3;         // k-range 0..3 (1024 k each)
  const int m     = lane & 15;
  const int q     = lane >> 4;
  const int row   = wg * ROWS_PER_WG + rb * 16 + m;

  __shared__ __align__(16) _Float16 cat[KCAT];      // [0,2048)=x_t [2048,4096)=h_{t-1}
  __shared__ __align__(16) float partials[8][16];   // [wave][row-in-16]
  __shared__ int sh_xcd, sh_relay;

  // ---- relay election on the REAL chiplet id (no mapping assumption) ----
  if (tid == 0) {
    int xid;
    asm volatile("s_getreg_b32 %0, hwreg(20, 0, 32)" : "=s"(xid));  // HW_REG_XCC_ID
    xid &= 7;
    int tk = __hip_atomic_fetch_add(&g_elect[layer][xid], 1, __ATOMIC_RELAXED,
                                    __HIP_MEMORY_SCOPE_AGENT);
    sh_xcd = xid;
    sh_relay = (tk == 0);
  }

  // ---- one-time: weights -> registers as fp16 A-fragments (128 VGPRs) ----
  // A layout (16x16x32): lane holds A[m][ktile + q*8 + j], j=0..7
  f32x4 afrag[NT];
  {
    const float* wl = wih + (size_t)layer * HID * HID + (size_t)row * HID;
    const float* wr = whh + (size_t)layer * HID * HID + (size_t)row * HID - HID;
#pragma unroll
    for (int i = 0; i < NT; ++i) {
      int kabs = kq * 1024 + i * 32 + q * 8;   // 1024-aligned ranges: never straddle 2048
      const float* src = (kabs < HID) ? (wl + kabs) : (wr + kabs);
      f32x4 w0 = *(const f32x4*)(src);
      f32x4 w1 = *(const f32x4*)(src + 4);
      f16x8 a;
      a[0] = (_Float16)w0[0]; a[1] = (_Float16)w0[1];
      a[2] = (_Float16)w0[2]; a[3] = (_Float16)w0[3];
      a[4] = (_Float16)w1[0]; a[5] = (_Float16)w1[1];
      a[6] = (_Float16)w1[2]; a[7] = (_Float16)w1[3];
      afrag[i] = __builtin_bit_cast(f32x4, a);
    }
#pragma unroll
    for (int i = 0; i < NT; ++i) asm volatile("" : "+v"(afrag[i]));  // pin
  }
  __syncthreads();
  const int  xcd      = sh_xcd;
  const bool is_relay = sh_relay != 0;
  int use_near = 1, near_fail = 0;    // per-thread mirror-health latch

  for (int t = 0; t < SEQ; ++t) {
    // ---- stage concat(x_t, h_{t-1}): relay pulls from IC + re-publishes to
    //      local L2; consumers poll the L2 mirror. Per-lane granularity. ----
    {
      u32x4 v = {0u, 0u, 0u, 0u};
      if (tid < 256) {
        if (layer == 0) {
          v = ((const u32x4*)(g_xin + (size_t)t * HID))[tid];
        } else {
          const u32x4* rsrc = (const u32x4*)&g_ring[layer - 1][t][0] + tid;
          u32x4*       mptr = (u32x4*)&g_mirror[layer - 1][xcd][t][0] + tid;
          const unsigned int exp = (unsigned int)(t & 1);
          v = is_relay ? relay_poll(rsrc, mptr, exp)
                       : cons_poll(mptr, rsrc, exp, use_near, near_fail);
        }
      } else if (t > 0) {
        const int i2 = tid - 256;
        const u32x4* rsrc = (const u32x4*)&g_ring[layer][t - 1][0] + i2;
        u32x4*       mptr = (u32x4*)&g_mirror[layer][xcd][t - 1][0] + i2;
        const unsigned int exp = (unsigned int)((t - 1) & 1);
        v = is_relay ? relay_poll(rsrc, mptr, exp)
                     : cons_poll(mptr, rsrc, exp, use_near, near_fail);
      }
      ((u32x4*)cat)[tid] = v;
    }
    __syncthreads();

    // ---- MFMA: 16 rows x own 1024-k range. B = h broadcast to 16 cols ----
    f32x4 acc0 = {0.f, 0.f, 0.f, 0.f}, acc1 = {0.f, 0.f, 0.f, 0.f};
    const f16x8* bb = (const f16x8*)cat;
#pragma unroll
    for (int i = 0; i < NT; i += 2) {
      f16x8 b0 = bb[kq * 128 + i * 4 + q];
      f16x8 b1 = bb[kq * 128 + (i + 1) * 4 + q];
      acc0 = __builtin_amdgcn_mfma_f32_16x16x32_f16(
          __builtin_bit_cast(f16x8, afrag[i]), b0, acc0, 0, 0, 0);
      acc1 = __builtin_amdgcn_mfma_f32_16x16x32_f16(
          __builtin_bit_cast(f16x8, afrag[i + 1]), b1, acc1, 0, 0, 0);
    }
    f32x4 accs = acc0 + acc1;
    // D layout: col=lane&15 (all equal), row=(lane>>4)*4+reg
    if (m == 0) *(f32x4*)&partials[wave][q * 4] = accs;
    __syncthreads();

    // ---- wave 0: reduce 4 k-partials per row, relu, publish (store == flag).
    //      Publish FIRST (serial path), out[] store after. ----
    if (tid < ROWS_PER_WG) {
      int rbb = tid >> 4, rr = tid & 15;
      float s = partials[rbb * 4 + 0][rr] + partials[rbb * 4 + 1][rr] +
                partials[rbb * 4 + 2][rr] + partials[rbb * 4 + 3][rr];
      s = fmaxf(s, 0.f);
      int gr = wg * ROWS_PER_WG + tid;
      unsigned int hb = (unsigned int)__builtin_bit_cast(unsigned short, (_Float16)s);
      unsigned int up = __shfl_down(hb, 1);          // odd row's bits
      if ((tid & 1) == 0) {
        unsigned int word = (hb & 0xFFFEu) | (unsigned int)(t & 1) | (up << 16);
        unsigned int* dst = (unsigned int*)&g_ring[layer][t][0] + (gr >> 1);
        __hip_atomic_store(dst, word, __ATOMIC_RELAXED, __HIP_MEMORY_SCOPE_AGENT);
      }
      if (layer == NL - 1) {
        out[(size_t)t * HID + gr] = s;                      // output[0, t, :]
        if (t == SEQ - 1) out[(size_t)SEQ * HID + gr] = s;  // h_last
      }
    }
    // no drain, no flag: the tagged store above is the publication.
  }
}

extern "C" void kernel_launch(void* const* d_in, const int* in_sizes, int n_in,
                              void* d_out, int out_size, void* d_ws, size_t ws_size,
                              hipStream_t stream) {
  const float* x   = (const float*)d_in[0];
  const float* wih = (const float*)d_in[1];
  const float* whh = (const float*)d_in[2];
  float* out = (float*)d_out;

  prep_kernel<<<65536, 1024, 0, stream>>>(x);
  rnn_kernel<<<NL * WGS_PER_LAYER, 512, 0, stream>>>(wih, whh, out);
}